// Round 11
// baseline (99.177 us; speedup 1.0000x reference)
//
#include <hip/hip_runtime.h>
#include <math.h>

// ============================ MFMA chamfer path ============================
// d(a,b) = |a|^2+|b|^2-2a.b computed ENTIRELY inside one
// mfma_f32_16x16x32_bf16 via hi/lo bf16 splitting and norm-folding:
//  A'[k0..12] = [-2ahx,-2ahy,-2ahz, -2ahx,-2ahy,-2ahz, -2alx,-2aly,-2alz, 1, 1, nh, nl]
//  B'[k0..12] = [ bhx, bhy, bhz,    blx, bly, blz,     bhx, bhy, bhz,  mh, ml, 1, 1]
//  dot = -2(ah.bh + ah.bl + al.bh) + (mh+ml) + (nh+nl) ~= d, err ~1e-4.
// Fragment layout (gfx950, m89/m92-verified family):
//  A: lane l holds A'[row=l&15, k=(l>>4)*8+j]; B: B'[k=(l>>4)*8+j, col=l&15];
//  C/D: row=(l>>4)*4+j, col=l&15.
typedef __attribute__((ext_vector_type(8))) short bf16x8;
typedef __attribute__((ext_vector_type(4))) float f32x4;
typedef __attribute__((ext_vector_type(4))) unsigned int uint4v;

#define ROWMIN_OFF 256
#define N_ROWMIN   106496            // f1 32768 | f2 32768 | c1 8192 | c2 32768
#define FRAG0      458752
#define SZ_FINE    (8*256*1024)
#define SZ_COARSE  (8*64*1024)
#define OFF_FINEA  ((size_t)FRAG0)
#define OFF_FINEB  ((size_t)FRAG0 + SZ_FINE)
#define OFF_GTA    ((size_t)FRAG0 + 2*(size_t)SZ_FINE)
#define OFF_GTB    ((size_t)FRAG0 + 3*(size_t)SZ_FINE)
#define OFF_COARA  ((size_t)FRAG0 + 4*(size_t)SZ_FINE)
#define OFF_COARB  ((size_t)FRAG0 + 4*(size_t)SZ_FINE + SZ_COARSE)
#define WS_NEED    ((size_t)FRAG0 + 4*(size_t)SZ_FINE + 2*(size_t)SZ_COARSE)

__device__ __forceinline__ unsigned short bf16_rn(float f) {
    unsigned u = __float_as_uint(f);
    u += 0x7FFFu + ((u >> 16) & 1u);
    return (unsigned short)(u >> 16);
}
__device__ __forceinline__ float bf16_f(unsigned short h) {
    return __uint_as_float(((unsigned)h) << 16);
}

__global__ __launch_bounds__(256) void prebuild(
    const float* __restrict__ fine, const float* __restrict__ gt,
    const float* __restrict__ coarse, unsigned* __restrict__ wsu)
{
    const int id = blockIdx.x * 256 + threadIdx.x;
    const int FRAGU = 8 * 1152 * 64;   // 589824 (b, role, 576 tiles, 64 lanes)
    char* wsc = (char*)wsu;
    if (id < FRAGU) {
        const int lane = id & 63;
        int t = (id >> 6) % 1152;
        const int b = (id >> 6) / 1152;
        const int role = (t >= 576) ? 1 : 0;   // 0 = as-A, 1 = as-B
        if (role) t -= 576;
        float x, y, z; size_t outoff;
        if (t < 256) {
            const float* p = fine + (size_t)b * 3 * 4096;
            int pt = t * 16 + (lane & 15);
            x = p[pt]; y = p[4096 + pt]; z = p[8192 + pt];
            outoff = (role ? OFF_FINEB : OFF_FINEA) + ((size_t)(b * 256 + t) * 64 + lane) * 16;
        } else if (t < 512) {
            int tile = t - 256;
            const float* p = gt + (size_t)b * 4096 * 3;
            int pt = tile * 16 + (lane & 15);
            x = p[3 * pt]; y = p[3 * pt + 1]; z = p[3 * pt + 2];
            outoff = (role ? OFF_GTB : OFF_GTA) + ((size_t)(b * 256 + tile) * 64 + lane) * 16;
        } else {
            int tile = t - 512;
            const float* p = coarse + (size_t)b * 3 * 1024;
            int pt = tile * 16 + (lane & 15);
            x = p[pt]; y = p[1024 + pt]; z = p[2048 + pt];
            outoff = (role ? OFF_COARB : OFF_COARA) + ((size_t)(b * 64 + tile) * 64 + lane) * 16;
        }
        const int kw = lane >> 4;
        unsigned short hx = bf16_rn(x), hy = bf16_rn(y), hz = bf16_rn(z);
        float fx = bf16_f(hx), fy = bf16_f(hy), fz = bf16_f(hz);
        unsigned short lx = bf16_rn(x - fx), ly = bf16_rn(y - fy), lz = bf16_rn(z - fz);
        float n = fmaf(x, x, fmaf(y, y, z * z));
        unsigned short nh = bf16_rn(n);
        unsigned short nl = bf16_rn(n - bf16_f(nh));
        const unsigned short one = 0x3F80;
        unsigned short e0=0,e1=0,e2=0,e3=0,e4=0,e5=0,e6=0,e7=0;
        if (kw < 2) {
            if (!role) {
                unsigned short t0 = bf16_rn(-2.f * fx), t1 = bf16_rn(-2.f * fy), t2 = bf16_rn(-2.f * fz);
                unsigned short u0 = bf16_rn(-2.f * bf16_f(lx)), u1 = bf16_rn(-2.f * bf16_f(ly)), u2 = bf16_rn(-2.f * bf16_f(lz));
                if (kw == 0) { e0=t0; e1=t1; e2=t2; e3=t0; e4=t1; e5=t2; e6=u0; e7=u1; }
                else         { e0=u2; e1=one; e2=one; e3=nh; e4=nl; }
            } else {
                if (kw == 0) { e0=hx; e1=hy; e2=hz; e3=lx; e4=ly; e5=lz; e6=hx; e7=hy; }
                else         { e0=hz; e1=nh; e2=nl; e3=one; e4=one; }
            }
        }
        uint4v v = { (unsigned)e0 | ((unsigned)e1 << 16),
                     (unsigned)e2 | ((unsigned)e3 << 16),
                     (unsigned)e4 | ((unsigned)e5 << 16),
                     (unsigned)e6 | ((unsigned)e7 << 16) };
        *(uint4v*)(wsc + outoff) = v;
    } else if (id < FRAGU + N_ROWMIN) {
        ((unsigned*)(wsc + ROWMIN_OFF))[id - FRAGU] = 0x7F800000u;  // +inf
    } else if (id == FRAGU + N_ROWMIN) {
        wsu[0] = 0u;  // float acc = 0
        wsu[1] = 0u;  // done counter
    }
}

// 5120 wave-units, all equal work (32 B-tile steps). Each wave: 8 A-strips
// (128 rows) x 512-col m-range; B-frag read amortized over 8 mfma.
__global__ __launch_bounds__(256, 4) void chamfer_mfma(unsigned char* __restrict__ wsb)
{
    const int w    = blockIdx.x * 4 + (threadIdx.x >> 6);
    const int lane = threadIdx.x & 63;

    int b, octet, ms, TA, TB, rowbase, rowsb;
    size_t Aoff, Boff;
    if (w < 2048)      { int u = w;        b = u >> 8; int r = u & 255; octet = r >> 3; ms = r & 7;
                         Aoff = OFF_FINEA; TA = 256; Boff = OFF_GTB;   TB = 256; rowbase = 0;     rowsb = 4096; }
    else if (w < 4096) { int u = w - 2048; b = u >> 8; int r = u & 255; octet = r >> 3; ms = r & 7;
                         Aoff = OFF_GTA;   TA = 256; Boff = OFF_FINEB; TB = 256; rowbase = 32768; rowsb = 4096; }
    else if (w < 4608) { int u = w - 4096; b = u >> 6; int r = u & 63;  octet = r >> 3; ms = r & 7;
                         Aoff = OFF_COARA; TA = 64;  Boff = OFF_GTB;   TB = 256; rowbase = 65536; rowsb = 1024; }
    else               { int u = w - 4608; b = u >> 6; int r = u & 63;  octet = r >> 1; ms = r & 1;
                         Aoff = OFF_GTA;   TA = 256; Boff = OFF_COARB; TB = 64;  rowbase = 73728; rowsb = 4096; }

    bf16x8 af[8];
#pragma unroll
    for (int s = 0; s < 8; ++s)
        af[s] = *(const bf16x8*)(wsb + Aoff + ((size_t)((b * TA + octet * 8 + s) * 64 + lane)) * 16);

    const unsigned char* bp = wsb + Boff + ((size_t)((b * TB + ms * 32) * 64 + lane)) * 16;

    float rm[8][4];
#pragma unroll
    for (int s = 0; s < 8; ++s) { rm[s][0]=rm[s][1]=rm[s][2]=rm[s][3]=3.402823466e38f; }

    const f32x4 zero = {0.f, 0.f, 0.f, 0.f};
#pragma unroll 2
    for (int mt = 0; mt < 32; ++mt) {
        bf16x8 bf = *(const bf16x8*)(bp + (size_t)mt * 1024);
#pragma unroll
        for (int s = 0; s < 8; ++s) {
            f32x4 r = __builtin_amdgcn_mfma_f32_16x16x32_bf16(af[s], bf, zero, 0, 0, 0);
            rm[s][0] = fminf(rm[s][0], r[0]);
            rm[s][1] = fminf(rm[s][1], r[1]);
            rm[s][2] = fminf(rm[s][2], r[2]);
            rm[s][3] = fminf(rm[s][3], r[3]);
        }
    }

    unsigned* rowmin = (unsigned*)(wsb + ROWMIN_OFF);
    const int rg = rowbase + b * rowsb + octet * 128;
#pragma unroll
    for (int s = 0; s < 8; ++s)
#pragma unroll
        for (int j = 0; j < 4; ++j) {
            float v = fmaxf(rm[s][j], 0.f);
            v = fminf(v, __shfl_xor(v, 1, 64));
            v = fminf(v, __shfl_xor(v, 2, 64));
            v = fminf(v, __shfl_xor(v, 4, 64));
            v = fminf(v, __shfl_xor(v, 8, 64));
            if ((lane & 15) == 0)
                atomicMin(rowmin + rg + s * 16 + (lane >> 4) * 4 + j, __float_as_uint(v));
        }
}

__global__ __launch_bounds__(256) void reduce_all(
    unsigned* __restrict__ wsu,
    const float* __restrict__ pred, const float* __restrict__ target,
    float* __restrict__ out)
{
    const unsigned* rowmin = (const unsigned*)((const char*)wsu + ROWMIN_OFF);
    const int tid = threadIdx.x;
    float s = 0.f;
    for (int i = blockIdx.x * 256 + tid; i < N_ROWMIN; i += gridDim.x * 256) {
        float v = __uint_as_float(rowmin[i]);
        float sc = (i >= 65536 && i < 73728) ? (1.f / 8192.f) : (1.f / 32768.f);
        s = fmaf(v, sc, s);
    }
    if (blockIdx.x == 0 && tid < 240) {
        float d = pred[tid] - target[tid];
        s = fmaf(d, d * (1.f / 240.f), s);
    }
    for (int off = 32; off > 0; off >>= 1) s += __shfl_down(s, off, 64);
    __shared__ float r4[4];
    if ((tid & 63) == 0) r4[tid >> 6] = s;
    __syncthreads();
    if (tid == 0) {
        atomicAdd((float*)wsu, r4[0] + r4[1] + r4[2] + r4[3]);
        __threadfence();
        unsigned old = atomicAdd(wsu + 1, 1u);
        if (old == gridDim.x - 1) {
            __threadfence();
            out[0] = atomicAdd((float*)wsu, 0.f);
        }
    }
}

// ===================== fallback: round-10 scan path (verified) =====================
#define SBMAX 2112
template<int CHUNK, bool A_PLANAR, bool B_PLANAR>
__device__ __forceinline__ float chamfer_block(
    const float* __restrict__ A, int An, const float* __restrict__ B, int Bn,
    int lbid, float scale, float (&sb)[4][SBMAX], float (&red)[512])
{
    constexpr int NSEG = 16;
    constexpr int SEG  = CHUNK / NSEG;
    constexpr int LOG_SEG = (CHUNK == 2048) ? 7 : 6;
    constexpr int SEGP = SEG + 4;
    const int bpb = An >> 5, batch = lbid / bpb, ablk = lbid % bpb;
    const float* __restrict__ Ab = A + (size_t)batch * 3 * An;
    const float* __restrict__ Bb = B + (size_t)batch * 3 * Bn;
    const int tid = threadIdx.x, slot = tid & 15, sp = tid >> 4;
    const int p0 = ablk * 32 + slot, p1 = p0 + 16;
    float a0x, a0y, a0z, a1x, a1y, a1z;
    if (A_PLANAR) { a0x=Ab[p0]; a0y=Ab[An+p0]; a0z=Ab[2*An+p0]; a1x=Ab[p1]; a1y=Ab[An+p1]; a1z=Ab[2*An+p1]; }
    else { a0x=Ab[3*p0]; a0y=Ab[3*p0+1]; a0z=Ab[3*p0+2]; a1x=Ab[3*p1]; a1y=Ab[3*p1+1]; a1z=Ab[3*p1+2]; }
    const float a0s = fmaf(a0x,a0x,fmaf(a0y,a0y,a0z*a0z));
    const float a1s = fmaf(a1x,a1x,fmaf(a1y,a1y,a1z*a1z));
    const float BIG = 3.402823466e38f;
    float n00=BIG,n01=BIG,n10=BIG,n11=BIG;
    for (int t0 = 0; t0 < Bn; t0 += CHUNK) {
#pragma unroll
        for (int i = 0; i < CHUNK / 256; ++i) {
            const int k = tid + i * 256; float x, y, z;
            if (B_PLANAR) { x=Bb[t0+k]; y=Bb[Bn+t0+k]; z=Bb[2*Bn+t0+k]; }
            else { int base = 3*(t0+k); x=Bb[base]; y=Bb[base+1]; z=Bb[base+2]; }
            const int addr = (k >> LOG_SEG) * SEGP + (k & (SEG - 1));
            sb[0][addr]=-2.f*x; sb[1][addr]=-2.f*y; sb[2][addr]=-2.f*z; sb[3][addr]=fmaf(x,x,fmaf(y,y,z*z));
        }
        __syncthreads();
        const float4* px = (const float4*)&sb[0][sp*SEGP];
        const float4* py = (const float4*)&sb[1][sp*SEGP];
        const float4* pz = (const float4*)&sb[2][sp*SEGP];
        const float4* pw = (const float4*)&sb[3][sp*SEGP];
#pragma unroll 2
        for (int g = 0; g < SEG / 4; ++g) {
            float4 x=px[g], y=py[g], z=pz[g], w=pw[g];
            float d0,d1,d2,d3;
            d0=fmaf(a0x,x.x,fmaf(a0y,y.x,fmaf(a0z,z.x,w.x)));
            d1=fmaf(a0x,x.y,fmaf(a0y,y.y,fmaf(a0z,z.y,w.y)));
            d2=fmaf(a0x,x.z,fmaf(a0y,y.z,fmaf(a0z,z.z,w.z)));
            d3=fmaf(a0x,x.w,fmaf(a0y,y.w,fmaf(a0z,z.w,w.w)));
            n00=fminf(fminf(d0,d1),n00); n01=fminf(fminf(d2,d3),n01);
            d0=fmaf(a1x,x.x,fmaf(a1y,y.x,fmaf(a1z,z.x,w.x)));
            d1=fmaf(a1x,x.y,fmaf(a1y,y.y,fmaf(a1z,z.y,w.y)));
            d2=fmaf(a1x,x.z,fmaf(a1y,y.z,fmaf(a1z,z.z,w.z)));
            d3=fmaf(a1x,x.w,fmaf(a1y,y.w,fmaf(a1z,z.w,w.w)));
            n10=fminf(fminf(d0,d1),n10); n11=fminf(fminf(d2,d3),n11);
        }
        __syncthreads();
    }
    red[sp*16+slot]=fminf(n00,n01); red[256+sp*16+slot]=fminf(n10,n11);
    __syncthreads();
#pragma unroll
    for (int st = 8; st > 0; st >>= 1) {
        if (sp < st) {
            red[sp*16+slot]=fminf(red[sp*16+slot],red[(sp+st)*16+slot]);
            red[256+sp*16+slot]=fminf(red[256+sp*16+slot],red[256+(sp+st)*16+slot]);
        }
        __syncthreads();
    }
    float contrib = 0.f;
    if (tid < 16) {
        float d = fmaxf(0.f,a0s+red[slot]) + fmaxf(0.f,a1s+red[256+slot]);
        d *= scale;
#pragma unroll
        for (int off = 8; off > 0; off >>= 1) d += __shfl_down(d, off, 16);
        contrib = d;
    }
    return contrib;
}

__device__ __forceinline__ float kp_block(const float* __restrict__ a,
                                          const float* __restrict__ b, int n, float (&red)[512])
{
    int tid = threadIdx.x; float s = 0.f;
    for (int i = tid; i < n; i += 256) { float d = a[i]-b[i]; s = fmaf(d,d,s); }
    for (int off = 32; off > 0; off >>= 1) s += __shfl_down(s, off, 64);
    if ((tid & 63) == 0) red[tid >> 6] = s;
    __syncthreads();
    float r = 0.f;
    if (tid == 0) r = (red[0]+red[1]+red[2]+red[3]) / (float)n;
    return r;
}

__global__ __launch_bounds__(256, 4) void fused_all(
    const float* __restrict__ pred, const float* __restrict__ target, int nkp,
    const float* __restrict__ coarse, int Nc, const float* __restrict__ fine, int Nf,
    const float* __restrict__ gt, int M, int r1, int r2, int r3, int r4,
    float sc_f1, float sc_f2, float sc_c1, float sc_c2, float* __restrict__ ws)
{
    __shared__ __align__(16) float sb[4][SBMAX];
    __shared__ float red[512];
    const int bid = blockIdx.x;
    float contrib;
    if (bid < r1)      contrib = chamfer_block<2048,true, false>(fine,  Nf, gt,     M,  bid,      sc_f1, sb, red);
    else if (bid < r2) contrib = chamfer_block<2048,false,true >(gt,    M,  fine,   Nf, bid - r1, sc_f2, sb, red);
    else if (bid < r3) contrib = chamfer_block<2048,true, false>(coarse,Nc, gt,     M,  bid - r2, sc_c1, sb, red);
    else if (bid < r4) contrib = chamfer_block<1024,false,true >(gt,    M,  coarse, Nc, bid - r3, sc_c2, sb, red);
    else               contrib = kp_block(pred, target, nkp, red);
    if (threadIdx.x == 0) ws[bid] = contrib;
}

__global__ __launch_bounds__(256) void finalize(const float* __restrict__ ws, int n,
                                                float* __restrict__ out)
{
    int tid = threadIdx.x; float s = 0.f;
    for (int i = tid; i < n; i += 256) s += ws[i];
    for (int off = 32; off > 0; off >>= 1) s += __shfl_down(s, off, 64);
    __shared__ float r[4];
    if ((tid & 63) == 0) r[tid >> 6] = s;
    __syncthreads();
    if (tid == 0) out[0] = r[0] + r[1] + r[2] + r[3];
}

// =================================== launch ===================================
extern "C" void kernel_launch(void* const* d_in, const int* in_sizes, int n_in,
                              void* d_out, int out_size, void* d_ws, size_t ws_size,
                              hipStream_t stream) {
    const float* pred   = (const float*)d_in[0];
    const float* target = (const float*)d_in[1];
    const float* coarse = (const float*)d_in[2]; // [B,3,Nc]
    const float* fine   = (const float*)d_in[3]; // [B,3,Nf]
    const float* gt     = (const float*)d_in[4]; // [B,M,3]
    float* out = (float*)d_out;

    const int nkp = in_sizes[0];
    const int B   = nkp / 30;
    const int Nc  = in_sizes[2] / (3 * B);
    const int Nf  = in_sizes[3] / (3 * B);
    const int M   = in_sizes[4] / (3 * B);

    const bool mfma_ok = (B == 8 && Nc == 1024 && Nf == 4096 && M == 4096 &&
                          ws_size >= WS_NEED);
    if (mfma_ok) {
        unsigned* wsu = (unsigned*)d_ws;
        const int FRAGU = 8 * 1152 * 64;
        const int pre_total = FRAGU + N_ROWMIN + 1;
        prebuild<<<(pre_total + 255) / 256, 256, 0, stream>>>(fine, gt, coarse, wsu);
        chamfer_mfma<<<1280, 256, 0, stream>>>((unsigned char*)d_ws);
        reduce_all<<<120, 256, 0, stream>>>(wsu, pred, target, out);
    } else {
        float* ws = (float*)d_ws;
        const int r1 = B * (Nf / 32);
        const int r2 = r1 + B * (M / 32);
        const int r3 = r2 + B * (Nc / 32);
        const int r4 = r3 + B * (M / 32);
        const int nb = r4 + 1;
        fused_all<<<nb, 256, 0, stream>>>(
            pred, target, nkp, coarse, Nc, fine, Nf, gt, M,
            r1, r2, r3, r4,
            1.0f / (B * Nf), 1.0f / (B * M), 1.0f / (B * Nc), 1.0f / (B * M), ws);
        finalize<<<1, 256, 0, stream>>>(ws, nb, out);
    }
}